// Round 11
// baseline (88.498 us; speedup 1.0000x reference)
//
#include <hip/hip_runtime.h>
#include <hip/hip_bf16.h>
#include <math.h>

#define N_NODES 50000
#define N_EDGES 1600000
#define IN_F 256
#define OUT_F 64

#define NB 196            // buckets (bucket = dst >> 8, 256 nodes each)
#define NBK 391           // bucket-scatter blocks, 4096 edges each
#define EPB 4096
#define RUN 64            // slots per (bucket, block) run; mean 20.9, +9.4 sigma
#define GEMM_BLOCKS 782   // 64 rows each
#define CSR_MAX 10752     // LDS csr capacity per bucket (mean 8192+pad<=1792, +5s)
#define MAXRUNS 25        // ceil(NBK / 16 waves)

typedef short short8 __attribute__((ext_vector_type(8)));
typedef unsigned short ushort8v __attribute__((ext_vector_type(8)));
typedef float f32x4 __attribute__((ext_vector_type(4)));

__device__ __forceinline__ unsigned short f2bf(float f) {
    union { __hip_bfloat16 h; unsigned short u; } v;
    v.h = __float2bfloat16(f);
    return v.u;
}
__device__ __forceinline__ float bf2f(unsigned u) {
    return __uint_as_float(u << 16);
}

// ---------------- K1: fused [gemm | bucket] ----------------
// Blocks 0..781: 64 rows of Wh = feat @ W^T (bf16 MFMA), fused el/er.
//   W converted fp32->bf16 fragment order into LDS directly (L2-resident),
//   feat fully prefetched (16 float4/lane), sched_barrier pins the cluster.
// Blocks 782..1172: bucket scatter into STATIC runs pairs[b][bk][RUN] with
//   LDS-only atomics; per-run counts to runcnt[bk][b]. No global atomics,
//   no init kernel needed.
__global__ __launch_bounds__(256) void k_main(const float* __restrict__ feat,
                                              const float* __restrict__ W,
                                              const float* __restrict__ att_w,
                                              unsigned short* __restrict__ whb,
                                              float* __restrict__ el,
                                              float* __restrict__ er,
                                              const int* __restrict__ src,
                                              const int* __restrict__ dst,
                                              unsigned* __restrict__ pairs,
                                              int* __restrict__ runcnt) {
    __shared__ unsigned short wlds[16384];  // 32 KB (gemm); aliased by bucket
    const int tid = threadIdx.x;

    if (blockIdx.x >= GEMM_BLOCKS) {
        // ---- bucket part ----
        int* lcur = (int*)wlds;
        const int bk = blockIdx.x - GEMM_BLOCKS;
        const int bbeg = bk * EPB;

        unsigned wreg[16];
        #pragma unroll
        for (int j = 0; j < 4; ++j) {
            int e0 = bbeg + j * 1024 + tid * 4;
            if (e0 + 3 < N_EDGES) {
                int4 dv = *(const int4*)(dst + e0);
                int4 sv = *(const int4*)(src + e0);
                wreg[j*4+0] = (unsigned)sv.x | ((unsigned)(dv.x & 255) << 16) | ((unsigned)(dv.x >> 8) << 24);
                wreg[j*4+1] = (unsigned)sv.y | ((unsigned)(dv.y & 255) << 16) | ((unsigned)(dv.y >> 8) << 24);
                wreg[j*4+2] = (unsigned)sv.z | ((unsigned)(dv.z & 255) << 16) | ((unsigned)(dv.z >> 8) << 24);
                wreg[j*4+3] = (unsigned)sv.w | ((unsigned)(dv.w & 255) << 16) | ((unsigned)(dv.w >> 8) << 24);
            } else {
                #pragma unroll
                for (int k = 0; k < 4; ++k) {
                    int e = e0 + k;
                    if (e < N_EDGES) {
                        int d = dst[e];
                        wreg[j*4+k] = (unsigned)src[e] | ((unsigned)(d & 255) << 16) | ((unsigned)(d >> 8) << 24);
                    } else wreg[j*4+k] = 0xFF000000u;  // sentinel bucket 255
                }
            }
        }
        for (int i = tid; i < NB; i += 256) lcur[i] = 0;
        __syncthreads();
        #pragma unroll
        for (int k = 0; k < 16; ++k) {
            unsigned wv = wreg[k];
            unsigned b = wv >> 24;
            if (b < NB) {
                int pos = atomicAdd(&lcur[b], 1);
                if (pos < RUN) pairs[((int)b * NBK + bk) * RUN + pos] = wv & 0x00FFFFFFu;
            }
        }
        __syncthreads();
        for (int i = tid; i < NB; i += 256) {
            int c = lcur[i];
            runcnt[bk * NB + i] = (c < RUN) ? c : RUN;
        }
        return;
    }

    // ---- gemm part: wave = 16 rows x 64 cols ----
    const int l = tid & 63, w = tid >> 6;
    const int l15 = l & 15, lg = l >> 4;
    const int wbase = blockIdx.x * 64 + w * 16;
    int ar = wbase + l15; if (ar > N_NODES - 1) ar = N_NODES - 1;
    const float* fbase = feat + (size_t)ar * IN_F + 8 * lg;

    // issue ALL 16 feat loads (full-tile MLP)
    float4 f[16];
    #pragma unroll
    for (int kt = 0; kt < 8; ++kt) {
        f[2*kt]   = *(const float4*)(fbase + kt * 32);
        f[2*kt+1] = *(const float4*)(fbase + kt * 32 + 4);
    }
    // stage W -> bf16 fragment-ordered LDS (W is 64 KB, L2-resident)
    #pragma unroll
    for (int i = 0; i < 8; ++i) {
        int c = tid + 256 * i;
        int ct = c >> 9, kt = (c >> 6) & 7, cl = c & 63;
        int col = ct * 16 + (cl & 15);
        int kb = kt * 32 + 8 * (cl >> 4);
        const float* p = W + col * 256 + kb;
        float4 x = *(const float4*)p;
        float4 y = *(const float4*)(p + 4);
        short8 v;
        v[0] = f2bf(x.x); v[1] = f2bf(x.y); v[2] = f2bf(x.z); v[3] = f2bf(x.w);
        v[4] = f2bf(y.x); v[5] = f2bf(y.y); v[6] = f2bf(y.z); v[7] = f2bf(y.w);
        *(short8*)(&wlds[c * 8]) = v;
    }
    __builtin_amdgcn_sched_barrier(0);   // pin: no load sinks below this point
    __syncthreads();

    f32x4 acc[4];
    #pragma unroll
    for (int ct = 0; ct < 4; ++ct) acc[ct] = (f32x4){0.f, 0.f, 0.f, 0.f};

    #pragma unroll
    for (int kt = 0; kt < 8; ++kt) {
        float4 fa = f[2*kt], fb = f[2*kt+1];
        short8 af;
        af[0] = f2bf(fa.x); af[1] = f2bf(fa.y); af[2] = f2bf(fa.z); af[3] = f2bf(fa.w);
        af[4] = f2bf(fb.x); af[5] = f2bf(fb.y); af[6] = f2bf(fb.z); af[7] = f2bf(fb.w);
        short8 b0 = *(const short8*)(&wlds[((0 * 8 + kt) * 64 + l) * 8]);
        short8 b1 = *(const short8*)(&wlds[((1 * 8 + kt) * 64 + l) * 8]);
        short8 b2 = *(const short8*)(&wlds[((2 * 8 + kt) * 64 + l) * 8]);
        short8 b3 = *(const short8*)(&wlds[((3 * 8 + kt) * 64 + l) * 8]);
        acc[0] = __builtin_amdgcn_mfma_f32_16x16x32_bf16(af, b0, acc[0], 0, 0, 0);
        acc[1] = __builtin_amdgcn_mfma_f32_16x16x32_bf16(af, b1, acc[1], 0, 0, 0);
        acc[2] = __builtin_amdgcn_mfma_f32_16x16x32_bf16(af, b2, acc[2], 0, 0, 0);
        acc[3] = __builtin_amdgcn_mfma_f32_16x16x32_bf16(af, b3, acc[3], 0, 0, 0);
    }

    float asrc[4], adst[4];
    #pragma unroll
    for (int ct = 0; ct < 4; ++ct) {
        asrc[ct] = att_w[ct * 16 + l15];
        adst[ct] = att_w[64 + ct * 16 + l15];
    }
    #pragma unroll
    for (int j = 0; j < 4; ++j) {
        int row = wbase + lg * 4 + j;
        float vs = 0.f, vd = 0.f;
        #pragma unroll
        for (int ct = 0; ct < 4; ++ct) {
            float v = acc[ct][j];
            vs += v * asrc[ct];
            vd += v * adst[ct];
            if (row < N_NODES) whb[(size_t)row * OUT_F + ct * 16 + l15] = f2bf(v);
        }
        vs += __shfl_xor(vs, 1); vd += __shfl_xor(vd, 1);
        vs += __shfl_xor(vs, 2); vd += __shfl_xor(vd, 2);
        vs += __shfl_xor(vs, 4); vd += __shfl_xor(vd, 4);
        vs += __shfl_xor(vs, 8); vd += __shfl_xor(vd, 8);
        if (l15 == 0 && row < N_NODES) { el[row] = vs; er[row] = vd; }
    }
}

// ---------------- K2: fused CSR-build + aggregate (one block per bucket) --
// 1024 threads = 16 waves. Runs staged into registers (ent[25], fully
// unrolled), counted + scanned in LDS, csr built IN LDS (never global),
// then wave w aggregates nodes w*16..w*16+15 with the 8-edge/VMEM scheme
// reading csr from LDS (8 words x 8-lane broadcast, conflict-free).
__global__ __launch_bounds__(1024) void k_fuse(const int* __restrict__ runcnt,
                                               const unsigned* __restrict__ pairs,
                                               const float* __restrict__ el,
                                               const float* __restrict__ er,
                                               const unsigned short* __restrict__ whb,
                                               const float* __restrict__ bias,
                                               float* __restrict__ out) {
    __shared__ unsigned csr[CSR_MAX];                 // 42 KB
    __shared__ int lcnt[256], ssc[256], lcur[256], obeg[256], olen[256];
    __shared__ float ler[256];
    const int b = blockIdx.x;
    const int t = threadIdx.x;
    const int w = t >> 6, lane = t & 63;

    for (int i = t; i < CSR_MAX; i += 1024) csr[i] = 0;
    if (t < 256) {
        lcnt[t] = 0;
        int node = b * 256 + t;
        ler[t] = (node < N_NODES) ? er[node] : 0.f;
    }
    __syncthreads();

    // load this wave's runs into registers + count per-node
    unsigned ent[MAXRUNS];
    #pragma unroll
    for (int it = 0; it < MAXRUNS; ++it) {
        int r = w + it * 16;
        unsigned e = 0xFFFFFFFFu;
        if (r < NBK) {
            int rc = runcnt[r * NB + b];
            if (lane < rc) e = pairs[(b * NBK + r) * RUN + lane];
        }
        ent[it] = e;
        if (e != 0xFFFFFFFFu) atomicAdd(&lcnt[(e >> 16) & 255], 1);
    }
    __syncthreads();

    // scan of 8-padded counts
    int pc = 0;
    if (t < 256) { pc = (lcnt[t] + 7) & ~7; ssc[t] = pc; }
    __syncthreads();
    for (int d = 1; d < 256; d <<= 1) {
        int v = 0;
        if (t < 256 && t >= d) v = ssc[t - d];
        __syncthreads();
        if (t < 256) ssc[t] += v;
        __syncthreads();
    }
    if (t < 256) {
        int base = ssc[t] - pc;
        lcur[t] = base;
        obeg[t] = base;
        olen[t] = pc;
    }
    __syncthreads();

    // scatter: p = exp(leaky(el[s]+er[n])); csr = s | bf16(p)<<16
    #pragma unroll
    for (int it = 0; it < MAXRUNS; ++it) {
        unsigned e = ent[it];
        if (e != 0xFFFFFFFFu) {
            int n8 = (e >> 16) & 255;
            int s = e & 0xFFFFu;
            float x = el[s] + ler[n8];
            x = (x > 0.f) ? x : 0.2f * x;
            float p = __expf(x);
            int pos = atomicAdd(&lcur[n8], 1);
            csr[pos] = (unsigned)s | ((unsigned)f2bf(p) << 16);
        }
    }
    __syncthreads();

    // aggregate: lane = (edge-slot es = l>>3, feature-group fg = l&7)
    const int fg = lane & 7, es = lane >> 3;
    for (int j = 0; j < 16; ++j) {
        int nl = w * 16 + j;
        int node = b * 256 + nl;
        if (node >= N_NODES) break;           // wave-uniform, no barriers inside
        int beg = obeg[nl], end = beg + olen[nl];
        float acc[8] = {0.f, 0.f, 0.f, 0.f, 0.f, 0.f, 0.f, 0.f};
        float den = 0.f;
        #pragma unroll 2
        for (int jj = beg; jj < end; jj += 8) {
            unsigned e = csr[jj + es];
            float p = __uint_as_float(e & 0xFFFF0000u);
            const unsigned short* wp = whb + (size_t)(e & 0xFFFFu) * OUT_F + fg * 8;
            ushort8v wv = *(const ushort8v*)wp;
            den += p;
            #pragma unroll
            for (int i = 0; i < 8; ++i) acc[i] = fmaf(p, bf2f((unsigned)wv[i]), acc[i]);
        }
        #pragma unroll
        for (int i = 0; i < 8; ++i) {
            acc[i] += __shfl_xor(acc[i], 8);
            acc[i] += __shfl_xor(acc[i], 16);
            acc[i] += __shfl_xor(acc[i], 32);
        }
        den += __shfl_xor(den, 8); den += __shfl_xor(den, 16); den += __shfl_xor(den, 32);

        if (es == 0) {
            float inv = (end > beg) ? 1.f / den : 0.f;
            ushort8v wn = *(const ushort8v*)(whb + (size_t)node * OUT_F + fg * 8);
            float4 b0 = *(const float4*)(bias + fg * 8);
            float4 b1 = *(const float4*)(bias + fg * 8 + 4);
            float h[8];
            h[0] = acc[0] * inv + bf2f((unsigned)wn[0]) + b0.x;
            h[1] = acc[1] * inv + bf2f((unsigned)wn[1]) + b0.y;
            h[2] = acc[2] * inv + bf2f((unsigned)wn[2]) + b0.z;
            h[3] = acc[3] * inv + bf2f((unsigned)wn[3]) + b0.w;
            h[4] = acc[4] * inv + bf2f((unsigned)wn[4]) + b1.x;
            h[5] = acc[5] * inv + bf2f((unsigned)wn[5]) + b1.y;
            h[6] = acc[6] * inv + bf2f((unsigned)wn[6]) + b1.z;
            h[7] = acc[7] * inv + bf2f((unsigned)wn[7]) + b1.w;
            #pragma unroll
            for (int i = 0; i < 8; ++i) h[i] = (h[i] > 0.f) ? h[i] : __expf(h[i]) - 1.f;
            float* op = out + (size_t)node * OUT_F + fg * 8;
            *(float4*)op = make_float4(h[0], h[1], h[2], h[3]);
            *(float4*)(op + 4) = make_float4(h[4], h[5], h[6], h[7]);
        }
    }
}

extern "C" void kernel_launch(void* const* d_in, const int* in_sizes, int n_in,
                              void* d_out, int out_size, void* d_ws, size_t ws_size,
                              hipStream_t stream) {
    const float* feat  = (const float*)d_in[0];
    const float* W     = (const float*)d_in[1];
    const float* att_w = (const float*)d_in[2];
    const float* bias  = (const float*)d_in[3];
    const int*   src   = (const int*)d_in[4];
    const int*   dst   = (const int*)d_in[5];
    float* out = (float*)d_out;

    // workspace layout (4-byte words)
    unsigned short* whb = (unsigned short*)d_ws;    // 3,200,000 bf16 = 1,600,000 words
    float* el       = (float*)d_ws + 1600000;       // 50,048
    float* er       = el + 50048;                   // 50,048
    unsigned* pairs = (unsigned*)(er + 50048);      // NB*NBK*RUN = 4,903,424 words
    int* runcnt     = (int*)(pairs + NB * NBK * RUN); // NBK*NB = 76,636 words
    // total ~26.7 MB

    k_main<<<GEMM_BLOCKS + NBK, 256, 0, stream>>>(feat, W, att_w, whb, el, er,
                                                  src, dst, pairs, runcnt);
    k_fuse<<<NB, 1024, 0, stream>>>(runcnt, pairs, el, er, whb, bias, out);
}

// Round 12
// 87.084 us; speedup vs baseline: 1.0162x; 1.0162x over previous
//
#include <hip/hip_runtime.h>
#include <hip/hip_bf16.h>
#include <math.h>

#define N_NODES 50000
#define N_EDGES 1600000
#define IN_F 256
#define OUT_F 64

#define NB 391            // buckets (bucket = dst >> 7, 128 nodes each)
#define CAP 6400          // per-bucket region stride (words) for pairs AND csr
#define BK_BLOCKS 391     // bucket-scatter blocks, 4096 edges each
#define EPB 4096
#define GEMM_BLOCKS 782   // 64 rows each

typedef short short8 __attribute__((ext_vector_type(8)));
typedef unsigned short ushort8v __attribute__((ext_vector_type(8)));
typedef float f32x4 __attribute__((ext_vector_type(4)));

__device__ __forceinline__ unsigned short f2bf(float f) {
    union { __hip_bfloat16 h; unsigned short u; } v;
    v.h = __float2bfloat16(f);
    return v.u;
}
__device__ __forceinline__ float bf2f(unsigned u) {
    return __uint_as_float(u << 16);
}

// ---------------- K1: fused [gemm | bucket] ----------------
// Blocks 0..781: 64 rows of Wh = feat @ W^T (bf16 MFMA), fused el/er.
//   W converted fp32->bf16 fragment order into LDS (L2-resident read),
//   feat fully prefetched (16 float4/lane), sched_barrier pins the cluster.
// Blocks 782..1172: bucket scatter. Packed word =
//   src | (d&127)<<16 | (d>>7)<<23 (bucket 9b). One global atomic per
//   (block,bucket) reserves a contiguous run in pairs[bucket*CAP ...].
__global__ __launch_bounds__(256) void k_main(const float* __restrict__ feat,
                                              const float* __restrict__ W,
                                              const float* __restrict__ att_w,
                                              unsigned short* __restrict__ whb,
                                              float* __restrict__ el,
                                              float* __restrict__ er,
                                              const int* __restrict__ src,
                                              const int* __restrict__ dst,
                                              int* __restrict__ cnt,
                                              unsigned* __restrict__ pairs) {
    __shared__ unsigned short wlds[16384];  // 32 KB (gemm); aliased by bucket
    const int tid = threadIdx.x;

    if (blockIdx.x >= GEMM_BLOCKS) {
        // ---- bucket part ----
        int* lhist = (int*)wlds;
        int* lcur  = lhist + 512;
        const int bbeg = (blockIdx.x - GEMM_BLOCKS) * EPB;

        unsigned wreg[16];
        #pragma unroll
        for (int j = 0; j < 4; ++j) {
            int e0 = bbeg + j * 1024 + tid * 4;
            if (e0 + 3 < N_EDGES) {
                int4 dv = *(const int4*)(dst + e0);
                int4 sv = *(const int4*)(src + e0);
                wreg[j*4+0] = (unsigned)sv.x | ((unsigned)(dv.x & 127) << 16) | ((unsigned)(dv.x >> 7) << 23);
                wreg[j*4+1] = (unsigned)sv.y | ((unsigned)(dv.y & 127) << 16) | ((unsigned)(dv.y >> 7) << 23);
                wreg[j*4+2] = (unsigned)sv.z | ((unsigned)(dv.z & 127) << 16) | ((unsigned)(dv.z >> 7) << 23);
                wreg[j*4+3] = (unsigned)sv.w | ((unsigned)(dv.w & 127) << 16) | ((unsigned)(dv.w >> 7) << 23);
            } else {
                #pragma unroll
                for (int k = 0; k < 4; ++k) {
                    int e = e0 + k;
                    if (e < N_EDGES) {
                        int d = dst[e];
                        wreg[j*4+k] = (unsigned)src[e] | ((unsigned)(d & 127) << 16) | ((unsigned)(d >> 7) << 23);
                    } else wreg[j*4+k] = 511u << 23;  // sentinel bucket
                }
            }
        }
        for (int i = tid; i < NB; i += 256) lhist[i] = 0;
        __syncthreads();
        #pragma unroll
        for (int k = 0; k < 16; ++k) {
            unsigned b = wreg[k] >> 23;
            if (b < NB) atomicAdd(&lhist[b], 1);
        }
        __syncthreads();
        for (int i = tid; i < NB; i += 256) {
            int c = lhist[i];
            lcur[i] = c ? (i * CAP + atomicAdd(&cnt[i], c)) : 0;
        }
        __syncthreads();
        #pragma unroll
        for (int k = 0; k < 16; ++k) {
            unsigned wv = wreg[k];
            unsigned b = wv >> 23;
            if (b < NB) {
                int pos = atomicAdd(&lcur[b], 1);
                pairs[pos] = wv & 0x007FFFFFu;
            }
        }
        return;
    }

    // ---- gemm part: wave = 16 rows x 64 cols ----
    const int l = tid & 63, w = tid >> 6;
    const int l15 = l & 15, lg = l >> 4;
    const int wbase = blockIdx.x * 64 + w * 16;
    int ar = wbase + l15; if (ar > N_NODES - 1) ar = N_NODES - 1;
    const float* fbase = feat + (size_t)ar * IN_F + 8 * lg;

    // issue ALL 16 feat loads (full-tile MLP)
    float4 f[16];
    #pragma unroll
    for (int kt = 0; kt < 8; ++kt) {
        f[2*kt]   = *(const float4*)(fbase + kt * 32);
        f[2*kt+1] = *(const float4*)(fbase + kt * 32 + 4);
    }
    // stage W -> bf16 fragment-ordered LDS (W is 64 KB, L2-resident)
    #pragma unroll
    for (int i = 0; i < 8; ++i) {
        int c = tid + 256 * i;
        int ct = c >> 9, kt = (c >> 6) & 7, cl = c & 63;
        int col = ct * 16 + (cl & 15);
        int kb = kt * 32 + 8 * (cl >> 4);
        const float* p = W + col * 256 + kb;
        float4 x = *(const float4*)p;
        float4 y = *(const float4*)(p + 4);
        short8 v;
        v[0] = f2bf(x.x); v[1] = f2bf(x.y); v[2] = f2bf(x.z); v[3] = f2bf(x.w);
        v[4] = f2bf(y.x); v[5] = f2bf(y.y); v[6] = f2bf(y.z); v[7] = f2bf(y.w);
        *(short8*)(&wlds[c * 8]) = v;
    }
    __builtin_amdgcn_sched_barrier(0);   // pin: no load sinks below this point
    __syncthreads();

    f32x4 acc[4];
    #pragma unroll
    for (int ct = 0; ct < 4; ++ct) acc[ct] = (f32x4){0.f, 0.f, 0.f, 0.f};

    #pragma unroll
    for (int kt = 0; kt < 8; ++kt) {
        float4 fa = f[2*kt], fb = f[2*kt+1];
        short8 af;
        af[0] = f2bf(fa.x); af[1] = f2bf(fa.y); af[2] = f2bf(fa.z); af[3] = f2bf(fa.w);
        af[4] = f2bf(fb.x); af[5] = f2bf(fb.y); af[6] = f2bf(fb.z); af[7] = f2bf(fb.w);
        short8 b0 = *(const short8*)(&wlds[((0 * 8 + kt) * 64 + l) * 8]);
        short8 b1 = *(const short8*)(&wlds[((1 * 8 + kt) * 64 + l) * 8]);
        short8 b2 = *(const short8*)(&wlds[((2 * 8 + kt) * 64 + l) * 8]);
        short8 b3 = *(const short8*)(&wlds[((3 * 8 + kt) * 64 + l) * 8]);
        acc[0] = __builtin_amdgcn_mfma_f32_16x16x32_bf16(af, b0, acc[0], 0, 0, 0);
        acc[1] = __builtin_amdgcn_mfma_f32_16x16x32_bf16(af, b1, acc[1], 0, 0, 0);
        acc[2] = __builtin_amdgcn_mfma_f32_16x16x32_bf16(af, b2, acc[2], 0, 0, 0);
        acc[3] = __builtin_amdgcn_mfma_f32_16x16x32_bf16(af, b3, acc[3], 0, 0, 0);
    }

    float asrc[4], adst[4];
    #pragma unroll
    for (int ct = 0; ct < 4; ++ct) {
        asrc[ct] = att_w[ct * 16 + l15];
        adst[ct] = att_w[64 + ct * 16 + l15];
    }
    #pragma unroll
    for (int j = 0; j < 4; ++j) {
        int row = wbase + lg * 4 + j;
        float vs = 0.f, vd = 0.f;
        #pragma unroll
        for (int ct = 0; ct < 4; ++ct) {
            float v = acc[ct][j];
            vs += v * asrc[ct];
            vd += v * adst[ct];
            if (row < N_NODES) whb[(size_t)row * OUT_F + ct * 16 + l15] = f2bf(v);
        }
        vs += __shfl_xor(vs, 1); vd += __shfl_xor(vd, 1);
        vs += __shfl_xor(vs, 2); vd += __shfl_xor(vd, 2);
        vs += __shfl_xor(vs, 4); vd += __shfl_xor(vd, 4);
        vs += __shfl_xor(vs, 8); vd += __shfl_xor(vd, 8);
        if (l15 == 0 && row < N_NODES) { el[row] = vs; er[row] = vd; }
    }
}

// ---------------- K2: level-2 CSR build (one block per 128-node bucket) ---
// csr word = src(16b) | p-as-bf16(16b), p = exp(leaky(el[src]+er[node])).
// Segments padded to multiples of 16 with zero entries for k_aggr.
__global__ __launch_bounds__(1024) void k_build(const int* __restrict__ cnt,
                                                const unsigned* __restrict__ pairs,
                                                const float* __restrict__ el,
                                                const float* __restrict__ er,
                                                int* __restrict__ offs,
                                                int* __restrict__ oend,
                                                unsigned* __restrict__ csr) {
    __shared__ int lcnt[128], ssc[128], lcur[128];
    __shared__ float ler[128];
    const int b = blockIdx.x;
    const int t = threadIdx.x;
    const int ebeg = b * CAP;
    const int nE = cnt[b];

    if (t < 128) {
        lcnt[t] = 0;
        int node = b * 128 + t;
        ler[t] = (node < N_NODES) ? er[node] : 0.f;
    }
    __syncthreads();
    for (int i = t; i < nE; i += 1024)
        atomicAdd(&lcnt[(pairs[ebeg + i] >> 16) & 127], 1);
    __syncthreads();
    if (t < 128) ssc[t] = (lcnt[t] + 15) & ~15;   // padded count (x16)
    __syncthreads();
    for (int d = 1; d < 128; d <<= 1) {
        int v = 0;
        if (t < 128 && t >= d) v = ssc[t - d];
        __syncthreads();
        if (t < 128) ssc[t] += v;
        __syncthreads();
    }
    if (t < 128) {
        int pc = (lcnt[t] + 15) & ~15;
        int base = ssc[t] - pc;               // 16-aligned
        lcur[t] = base;
        int node = b * 128 + t;
        if (node < N_NODES) { offs[node] = ebeg + base; oend[node] = ebeg + base + pc; }
        for (int k = lcnt[t]; k < pc; ++k) csr[ebeg + base + k] = 0;  // pad
    }
    __syncthreads();
    for (int i = t; i < nE; i += 1024) {
        unsigned v = pairs[ebeg + i];
        int n7 = (v >> 16) & 127;
        int s = v & 0xFFFFu;
        float e = el[s] + ler[n7];
        e = (e > 0.f) ? e : 0.2f * e;
        float p = __expf(e);
        int pos = atomicAdd(&lcur[n7], 1);
        csr[ebeg + pos] = (unsigned)s | ((unsigned)f2bf(p) << 16);
    }
}

// ---------------- K3: per-node gather — 16 edges/iter, dual chains -------
// Wave per node. lane = (edge-slot es = l>>3, feature-group fg = l&7).
// Two independent csr broadcast words + two independent 16B row loads per
// iteration -> 2x memory-level parallelism. Segments 16-padded.
__global__ __launch_bounds__(256) void k_aggr(const int* __restrict__ offs,
                                              const int* __restrict__ oend,
                                              const unsigned* __restrict__ csr,
                                              const unsigned short* __restrict__ whb,
                                              const float* __restrict__ bias,
                                              float* __restrict__ out) {
    const int wid = __builtin_amdgcn_readfirstlane(threadIdx.x >> 6);
    const int node = blockIdx.x * 4 + wid;
    const int lane = threadIdx.x & 63;
    const int fg = lane & 7, es = lane >> 3;
    const int beg = offs[node], end = oend[node];

    float acc[8] = {0.f, 0.f, 0.f, 0.f, 0.f, 0.f, 0.f, 0.f};
    float den = 0.f;
    for (int jj = beg; jj < end; jj += 16) {
        unsigned e0 = csr[jj + es];
        unsigned e1 = csr[jj + 8 + es];
        float p0 = __uint_as_float(e0 & 0xFFFF0000u);
        float p1 = __uint_as_float(e1 & 0xFFFF0000u);
        ushort8v wv0 = *(const ushort8v*)(whb + (size_t)(e0 & 0xFFFFu) * OUT_F + fg * 8);
        ushort8v wv1 = *(const ushort8v*)(whb + (size_t)(e1 & 0xFFFFu) * OUT_F + fg * 8);
        den += p0 + p1;
        #pragma unroll
        for (int i = 0; i < 8; ++i) acc[i] = fmaf(p0, bf2f((unsigned)wv0[i]), acc[i]);
        #pragma unroll
        for (int i = 0; i < 8; ++i) acc[i] = fmaf(p1, bf2f((unsigned)wv1[i]), acc[i]);
    }
    #pragma unroll
    for (int i = 0; i < 8; ++i) {
        acc[i] += __shfl_xor(acc[i], 8);
        acc[i] += __shfl_xor(acc[i], 16);
        acc[i] += __shfl_xor(acc[i], 32);
    }
    den += __shfl_xor(den, 8); den += __shfl_xor(den, 16); den += __shfl_xor(den, 32);

    if (es == 0) {
        float inv = (end > beg) ? 1.f / den : 0.f;
        ushort8v wn = *(const ushort8v*)(whb + (size_t)node * OUT_F + fg * 8);
        float4 b0 = *(const float4*)(bias + fg * 8);
        float4 b1 = *(const float4*)(bias + fg * 8 + 4);
        float h[8];
        h[0] = acc[0] * inv + bf2f((unsigned)wn[0]) + b0.x;
        h[1] = acc[1] * inv + bf2f((unsigned)wn[1]) + b0.y;
        h[2] = acc[2] * inv + bf2f((unsigned)wn[2]) + b0.z;
        h[3] = acc[3] * inv + bf2f((unsigned)wn[3]) + b0.w;
        h[4] = acc[4] * inv + bf2f((unsigned)wn[4]) + b1.x;
        h[5] = acc[5] * inv + bf2f((unsigned)wn[5]) + b1.y;
        h[6] = acc[6] * inv + bf2f((unsigned)wn[6]) + b1.z;
        h[7] = acc[7] * inv + bf2f((unsigned)wn[7]) + b1.w;
        #pragma unroll
        for (int i = 0; i < 8; ++i) h[i] = (h[i] > 0.f) ? h[i] : __expf(h[i]) - 1.f;
        float* op = out + (size_t)node * OUT_F + fg * 8;
        *(float4*)op = make_float4(h[0], h[1], h[2], h[3]);
        *(float4*)(op + 4) = make_float4(h[4], h[5], h[6], h[7]);
    }
}

extern "C" void kernel_launch(void* const* d_in, const int* in_sizes, int n_in,
                              void* d_out, int out_size, void* d_ws, size_t ws_size,
                              hipStream_t stream) {
    const float* feat  = (const float*)d_in[0];
    const float* W     = (const float*)d_in[1];
    const float* att_w = (const float*)d_in[2];
    const float* bias  = (const float*)d_in[3];
    const int*   src   = (const int*)d_in[4];
    const int*   dst   = (const int*)d_in[5];
    float* out = (float*)d_out;

    // workspace layout (4-byte words)
    unsigned short* whb = (unsigned short*)d_ws;    // 3,200,000 bf16 = 1,600,000 words
    float* el       = (float*)d_ws + 1600000;       // 50,048
    float* er       = el + 50048;                   // 50,048
    int*   offs     = (int*)(er + 50048);           // 50,048
    int*   oend     = offs + 50048;                 // 50,048
    int*   cnt      = oend + 50048;                 // 512
    unsigned* pairs = (unsigned*)(cnt + 512);       // NB*CAP = 2,502,400 words
    unsigned* csr   = pairs + NB * CAP;             // 2,502,400 words
    // total ~27.2 MB

    hipMemsetAsync(cnt, 0, NB * sizeof(int), stream);
    k_main<<<GEMM_BLOCKS + BK_BLOCKS, 256, 0, stream>>>(feat, W, att_w, whb, el, er,
                                                        src, dst, cnt, pairs);
    k_build<<<NB, 1024, 0, stream>>>(cnt, pairs, el, er, offs, oend, csr);
    k_aggr<<<N_NODES / 4, 256, 0, stream>>>(offs, oend, csr, whb, bias, out);
}

// Round 13
// 85.466 us; speedup vs baseline: 1.0355x; 1.0189x over previous
//
#include <hip/hip_runtime.h>
#include <hip/hip_bf16.h>
#include <math.h>

#define N_NODES 50000
#define N_EDGES 1600000
#define IN_F 256
#define OUT_F 64

#define NB 391            // buckets (bucket = dst >> 7, 128 nodes each)
#define CAP 6400          // per-bucket region stride (words) for pairs AND csr
#define BK_BLOCKS 391     // bucket-scatter blocks, 4096 edges each
#define EPB 4096
#define GEMM_BLOCKS 782   // 64 rows each

typedef short short8 __attribute__((ext_vector_type(8)));
typedef unsigned short ushort8v __attribute__((ext_vector_type(8)));
typedef float f32x4 __attribute__((ext_vector_type(4)));

__device__ __forceinline__ unsigned short f2bf(float f) {
    union { __hip_bfloat16 h; unsigned short u; } v;
    v.h = __float2bfloat16(f);
    return v.u;
}
__device__ __forceinline__ float bf2f(unsigned u) {
    return __uint_as_float(u << 16);
}

// ---------------- K0: zero the bucket counters (replaces hipMemsetAsync,
// whose tiny fill dispatch cost ~39 us in the graph-replay path) ----------
__global__ __launch_bounds__(512) void k_zero(int* __restrict__ cnt) {
    int t = threadIdx.x;
    if (t < NB) cnt[t] = 0;
}

// ---------------- K1: fused [gemm | bucket] ----------------
// Blocks 0..781: 64 rows of Wh = feat @ W^T (bf16 MFMA), fused el/er.
//   W converted fp32->bf16 fragment order into LDS (L2-resident read),
//   feat fully prefetched (16 float4/lane), sched_barrier pins the cluster.
// Blocks 782..1172: bucket scatter. Packed word =
//   src | (d&127)<<16 | (d>>7)<<23 (bucket 9b). One global atomic per
//   (block,bucket) reserves a contiguous run in pairs[bucket*CAP ...].
__global__ __launch_bounds__(256) void k_main(const float* __restrict__ feat,
                                              const float* __restrict__ W,
                                              const float* __restrict__ att_w,
                                              unsigned short* __restrict__ whb,
                                              float* __restrict__ el,
                                              float* __restrict__ er,
                                              const int* __restrict__ src,
                                              const int* __restrict__ dst,
                                              int* __restrict__ cnt,
                                              unsigned* __restrict__ pairs) {
    __shared__ unsigned short wlds[16384];  // 32 KB (gemm); aliased by bucket
    const int tid = threadIdx.x;

    if (blockIdx.x >= GEMM_BLOCKS) {
        // ---- bucket part ----
        int* lhist = (int*)wlds;
        int* lcur  = lhist + 512;
        const int bbeg = (blockIdx.x - GEMM_BLOCKS) * EPB;

        unsigned wreg[16];
        #pragma unroll
        for (int j = 0; j < 4; ++j) {
            int e0 = bbeg + j * 1024 + tid * 4;
            if (e0 + 3 < N_EDGES) {
                int4 dv = *(const int4*)(dst + e0);
                int4 sv = *(const int4*)(src + e0);
                wreg[j*4+0] = (unsigned)sv.x | ((unsigned)(dv.x & 127) << 16) | ((unsigned)(dv.x >> 7) << 23);
                wreg[j*4+1] = (unsigned)sv.y | ((unsigned)(dv.y & 127) << 16) | ((unsigned)(dv.y >> 7) << 23);
                wreg[j*4+2] = (unsigned)sv.z | ((unsigned)(dv.z & 127) << 16) | ((unsigned)(dv.z >> 7) << 23);
                wreg[j*4+3] = (unsigned)sv.w | ((unsigned)(dv.w & 127) << 16) | ((unsigned)(dv.w >> 7) << 23);
            } else {
                #pragma unroll
                for (int k = 0; k < 4; ++k) {
                    int e = e0 + k;
                    if (e < N_EDGES) {
                        int d = dst[e];
                        wreg[j*4+k] = (unsigned)src[e] | ((unsigned)(d & 127) << 16) | ((unsigned)(d >> 7) << 23);
                    } else wreg[j*4+k] = 511u << 23;  // sentinel bucket
                }
            }
        }
        for (int i = tid; i < NB; i += 256) lhist[i] = 0;
        __syncthreads();
        #pragma unroll
        for (int k = 0; k < 16; ++k) {
            unsigned b = wreg[k] >> 23;
            if (b < NB) atomicAdd(&lhist[b], 1);
        }
        __syncthreads();
        for (int i = tid; i < NB; i += 256) {
            int c = lhist[i];
            lcur[i] = c ? (i * CAP + atomicAdd(&cnt[i], c)) : 0;
        }
        __syncthreads();
        #pragma unroll
        for (int k = 0; k < 16; ++k) {
            unsigned wv = wreg[k];
            unsigned b = wv >> 23;
            if (b < NB) {
                int pos = atomicAdd(&lcur[b], 1);
                pairs[pos] = wv & 0x007FFFFFu;
            }
        }
        return;
    }

    // ---- gemm part: wave = 16 rows x 64 cols ----
    const int l = tid & 63, w = tid >> 6;
    const int l15 = l & 15, lg = l >> 4;
    const int wbase = blockIdx.x * 64 + w * 16;
    int ar = wbase + l15; if (ar > N_NODES - 1) ar = N_NODES - 1;
    const float* fbase = feat + (size_t)ar * IN_F + 8 * lg;

    // issue ALL 16 feat loads (full-tile MLP)
    float4 f[16];
    #pragma unroll
    for (int kt = 0; kt < 8; ++kt) {
        f[2*kt]   = *(const float4*)(fbase + kt * 32);
        f[2*kt+1] = *(const float4*)(fbase + kt * 32 + 4);
    }
    // stage W -> bf16 fragment-ordered LDS (W is 64 KB, L2-resident)
    #pragma unroll
    for (int i = 0; i < 8; ++i) {
        int c = tid + 256 * i;
        int ct = c >> 9, kt = (c >> 6) & 7, cl = c & 63;
        int col = ct * 16 + (cl & 15);
        int kb = kt * 32 + 8 * (cl >> 4);
        const float* p = W + col * 256 + kb;
        float4 x = *(const float4*)p;
        float4 y = *(const float4*)(p + 4);
        short8 v;
        v[0] = f2bf(x.x); v[1] = f2bf(x.y); v[2] = f2bf(x.z); v[3] = f2bf(x.w);
        v[4] = f2bf(y.x); v[5] = f2bf(y.y); v[6] = f2bf(y.z); v[7] = f2bf(y.w);
        *(short8*)(&wlds[c * 8]) = v;
    }
    __builtin_amdgcn_sched_barrier(0);   // pin: no load sinks below this point
    __syncthreads();

    f32x4 acc[4];
    #pragma unroll
    for (int ct = 0; ct < 4; ++ct) acc[ct] = (f32x4){0.f, 0.f, 0.f, 0.f};

    #pragma unroll
    for (int kt = 0; kt < 8; ++kt) {
        float4 fa = f[2*kt], fb = f[2*kt+1];
        short8 af;
        af[0] = f2bf(fa.x); af[1] = f2bf(fa.y); af[2] = f2bf(fa.z); af[3] = f2bf(fa.w);
        af[4] = f2bf(fb.x); af[5] = f2bf(fb.y); af[6] = f2bf(fb.z); af[7] = f2bf(fb.w);
        short8 b0 = *(const short8*)(&wlds[((0 * 8 + kt) * 64 + l) * 8]);
        short8 b1 = *(const short8*)(&wlds[((1 * 8 + kt) * 64 + l) * 8]);
        short8 b2 = *(const short8*)(&wlds[((2 * 8 + kt) * 64 + l) * 8]);
        short8 b3 = *(const short8*)(&wlds[((3 * 8 + kt) * 64 + l) * 8]);
        acc[0] = __builtin_amdgcn_mfma_f32_16x16x32_bf16(af, b0, acc[0], 0, 0, 0);
        acc[1] = __builtin_amdgcn_mfma_f32_16x16x32_bf16(af, b1, acc[1], 0, 0, 0);
        acc[2] = __builtin_amdgcn_mfma_f32_16x16x32_bf16(af, b2, acc[2], 0, 0, 0);
        acc[3] = __builtin_amdgcn_mfma_f32_16x16x32_bf16(af, b3, acc[3], 0, 0, 0);
    }

    float asrc[4], adst[4];
    #pragma unroll
    for (int ct = 0; ct < 4; ++ct) {
        asrc[ct] = att_w[ct * 16 + l15];
        adst[ct] = att_w[64 + ct * 16 + l15];
    }
    #pragma unroll
    for (int j = 0; j < 4; ++j) {
        int row = wbase + lg * 4 + j;
        float vs = 0.f, vd = 0.f;
        #pragma unroll
        for (int ct = 0; ct < 4; ++ct) {
            float v = acc[ct][j];
            vs += v * asrc[ct];
            vd += v * adst[ct];
            if (row < N_NODES) whb[(size_t)row * OUT_F + ct * 16 + l15] = f2bf(v);
        }
        vs += __shfl_xor(vs, 1); vd += __shfl_xor(vd, 1);
        vs += __shfl_xor(vs, 2); vd += __shfl_xor(vd, 2);
        vs += __shfl_xor(vs, 4); vd += __shfl_xor(vd, 4);
        vs += __shfl_xor(vs, 8); vd += __shfl_xor(vd, 8);
        if (l15 == 0 && row < N_NODES) { el[row] = vs; er[row] = vd; }
    }
}

// ---------------- K2: level-2 CSR build (one block per 128-node bucket) ---
// csr word = src(16b) | p-as-bf16(16b), p = exp(leaky(el[src]+er[node])).
// Segments padded to multiples of 16 with zero entries for k_aggr.
__global__ __launch_bounds__(1024) void k_build(const int* __restrict__ cnt,
                                                const unsigned* __restrict__ pairs,
                                                const float* __restrict__ el,
                                                const float* __restrict__ er,
                                                int* __restrict__ offs,
                                                int* __restrict__ oend,
                                                unsigned* __restrict__ csr) {
    __shared__ int lcnt[128], ssc[128], lcur[128];
    __shared__ float ler[128];
    const int b = blockIdx.x;
    const int t = threadIdx.x;
    const int ebeg = b * CAP;
    const int nE = cnt[b];

    if (t < 128) {
        lcnt[t] = 0;
        int node = b * 128 + t;
        ler[t] = (node < N_NODES) ? er[node] : 0.f;
    }
    __syncthreads();
    for (int i = t; i < nE; i += 1024)
        atomicAdd(&lcnt[(pairs[ebeg + i] >> 16) & 127], 1);
    __syncthreads();
    if (t < 128) ssc[t] = (lcnt[t] + 15) & ~15;   // padded count (x16)
    __syncthreads();
    for (int d = 1; d < 128; d <<= 1) {
        int v = 0;
        if (t < 128 && t >= d) v = ssc[t - d];
        __syncthreads();
        if (t < 128) ssc[t] += v;
        __syncthreads();
    }
    if (t < 128) {
        int pc = (lcnt[t] + 15) & ~15;
        int base = ssc[t] - pc;               // 16-aligned
        lcur[t] = base;
        int node = b * 128 + t;
        if (node < N_NODES) { offs[node] = ebeg + base; oend[node] = ebeg + base + pc; }
        for (int k = lcnt[t]; k < pc; ++k) csr[ebeg + base + k] = 0;  // pad
    }
    __syncthreads();
    for (int i = t; i < nE; i += 1024) {
        unsigned v = pairs[ebeg + i];
        int n7 = (v >> 16) & 127;
        int s = v & 0xFFFFu;
        float e = el[s] + ler[n7];
        e = (e > 0.f) ? e : 0.2f * e;
        float p = __expf(e);
        int pos = atomicAdd(&lcur[n7], 1);
        csr[ebeg + pos] = (unsigned)s | ((unsigned)f2bf(p) << 16);
    }
}

// ---------------- K3: per-node gather — 16 edges/iter, dual chains -------
// Wave per node. lane = (edge-slot es = l>>3, feature-group fg = l&7).
// Two independent csr broadcast words + two independent 16B row loads per
// iteration -> 2x memory-level parallelism. Segments 16-padded.
__global__ __launch_bounds__(256) void k_aggr(const int* __restrict__ offs,
                                              const int* __restrict__ oend,
                                              const unsigned* __restrict__ csr,
                                              const unsigned short* __restrict__ whb,
                                              const float* __restrict__ bias,
                                              float* __restrict__ out) {
    const int wid = __builtin_amdgcn_readfirstlane(threadIdx.x >> 6);
    const int node = blockIdx.x * 4 + wid;
    const int lane = threadIdx.x & 63;
    const int fg = lane & 7, es = lane >> 3;
    const int beg = offs[node], end = oend[node];

    float acc[8] = {0.f, 0.f, 0.f, 0.f, 0.f, 0.f, 0.f, 0.f};
    float den = 0.f;
    for (int jj = beg; jj < end; jj += 16) {
        unsigned e0 = csr[jj + es];
        unsigned e1 = csr[jj + 8 + es];
        float p0 = __uint_as_float(e0 & 0xFFFF0000u);
        float p1 = __uint_as_float(e1 & 0xFFFF0000u);
        ushort8v wv0 = *(const ushort8v*)(whb + (size_t)(e0 & 0xFFFFu) * OUT_F + fg * 8);
        ushort8v wv1 = *(const ushort8v*)(whb + (size_t)(e1 & 0xFFFFu) * OUT_F + fg * 8);
        den += p0 + p1;
        #pragma unroll
        for (int i = 0; i < 8; ++i) acc[i] = fmaf(p0, bf2f((unsigned)wv0[i]), acc[i]);
        #pragma unroll
        for (int i = 0; i < 8; ++i) acc[i] = fmaf(p1, bf2f((unsigned)wv1[i]), acc[i]);
    }
    #pragma unroll
    for (int i = 0; i < 8; ++i) {
        acc[i] += __shfl_xor(acc[i], 8);
        acc[i] += __shfl_xor(acc[i], 16);
        acc[i] += __shfl_xor(acc[i], 32);
    }
    den += __shfl_xor(den, 8); den += __shfl_xor(den, 16); den += __shfl_xor(den, 32);

    if (es == 0) {
        float inv = (end > beg) ? 1.f / den : 0.f;
        ushort8v wn = *(const ushort8v*)(whb + (size_t)node * OUT_F + fg * 8);
        float4 b0 = *(const float4*)(bias + fg * 8);
        float4 b1 = *(const float4*)(bias + fg * 8 + 4);
        float h[8];
        h[0] = acc[0] * inv + bf2f((unsigned)wn[0]) + b0.x;
        h[1] = acc[1] * inv + bf2f((unsigned)wn[1]) + b0.y;
        h[2] = acc[2] * inv + bf2f((unsigned)wn[2]) + b0.z;
        h[3] = acc[3] * inv + bf2f((unsigned)wn[3]) + b0.w;
        h[4] = acc[4] * inv + bf2f((unsigned)wn[4]) + b1.x;
        h[5] = acc[5] * inv + bf2f((unsigned)wn[5]) + b1.y;
        h[6] = acc[6] * inv + bf2f((unsigned)wn[6]) + b1.z;
        h[7] = acc[7] * inv + bf2f((unsigned)wn[7]) + b1.w;
        #pragma unroll
        for (int i = 0; i < 8; ++i) h[i] = (h[i] > 0.f) ? h[i] : __expf(h[i]) - 1.f;
        float* op = out + (size_t)node * OUT_F + fg * 8;
        *(float4*)op = make_float4(h[0], h[1], h[2], h[3]);
        *(float4*)(op + 4) = make_float4(h[4], h[5], h[6], h[7]);
    }
}

extern "C" void kernel_launch(void* const* d_in, const int* in_sizes, int n_in,
                              void* d_out, int out_size, void* d_ws, size_t ws_size,
                              hipStream_t stream) {
    const float* feat  = (const float*)d_in[0];
    const float* W     = (const float*)d_in[1];
    const float* att_w = (const float*)d_in[2];
    const float* bias  = (const float*)d_in[3];
    const int*   src   = (const int*)d_in[4];
    const int*   dst   = (const int*)d_in[5];
    float* out = (float*)d_out;

    // workspace layout (4-byte words)
    unsigned short* whb = (unsigned short*)d_ws;    // 3,200,000 bf16 = 1,600,000 words
    float* el       = (float*)d_ws + 1600000;       // 50,048
    float* er       = el + 50048;                   // 50,048
    int*   offs     = (int*)(er + 50048);           // 50,048
    int*   oend     = offs + 50048;                 // 50,048
    int*   cnt      = oend + 50048;                 // 512
    unsigned* pairs = (unsigned*)(cnt + 512);       // NB*CAP = 2,502,400 words
    unsigned* csr   = pairs + NB * CAP;             // 2,502,400 words
    // total ~27.2 MB

    k_zero<<<1, 512, 0, stream>>>(cnt);
    k_main<<<GEMM_BLOCKS + BK_BLOCKS, 256, 0, stream>>>(feat, W, att_w, whb, el, er,
                                                        src, dst, cnt, pairs);
    k_build<<<NB, 1024, 0, stream>>>(cnt, pairs, el, er, offs, oend, csr);
    k_aggr<<<N_NODES / 4, 256, 0, stream>>>(offs, oend, csr, whb, bias, out);
}